// Round 1
// 489.958 us; speedup vs baseline: 1.1603x; 1.1603x over previous
//
#include <hip/hip_runtime.h>
#include <hip/hip_bf16.h>
#include <stdint.h>

// out[m,n] = sum_k x[m,k] * (W[n,k] + sum_r down[n,r]*up[r,k]) + bias[n]
// M=8192, N=4096, K=4096, R=16, fp32 I/O.
// Round 4: GEMM rewritten to the 256x256-tile, BK=64, 8-wave, 8-phase schedule
// with counted vmcnt (never 0 in the main loop), granule-XOR LDS swizzle,
// s_setprio around MFMA clusters, bijective XCD blockIdx swizzle.
// Race-free staging order: A(kt+1) staged in phases 0-1 (its buffer's A region
// last read at kt-1, freed by kt-1's final barrier); B(kt+2) staged in phases
// 2-3 (current buffer's B region dead after phase 0 -- all B frags hoisted to
// registers at phase 0). vmcnt(4) at end of each K-tile guarantees kt+1 fully
// landed while kt+2's B stays in flight.

typedef __attribute__((ext_vector_type(4))) float  floatx4;
typedef __attribute__((ext_vector_type(8))) __bf16 bf16x8;

static __device__ __forceinline__ unsigned short f2bf_rne(float f) {
    union { float f; uint32_t u; } v; v.f = f;
    uint32_t r = v.u + 0x7fffu + ((v.u >> 16) & 1u);
    return (unsigned short)(r >> 16);
}

// ---------------- x fp32 -> bf16, fully coalesced (float4 -> uint2) ----------------
__global__ __launch_bounds__(256) void cvt_x_kernel(const float4* __restrict__ x4,
                                                    uint2* __restrict__ o2,
                                                    int n4) {
    const int stride = gridDim.x * 256;
    for (int i = blockIdx.x * 256 + threadIdx.x; i < n4; i += stride) {
        float4 a = x4[i];
        union { unsigned short s[4]; uint2 v; } o;
        o.s[0] = f2bf_rne(a.x); o.s[1] = f2bf_rne(a.y);
        o.s[2] = f2bf_rne(a.z); o.s[3] = f2bf_rne(a.w);
        o2[i] = o.v;
    }
}

// ------------- merged weight: Wb[n,k] = bf16(W[n,k] + sum_r d[n,r]*up[r,k]) -------------
#define MW_ROWS 16
__global__ __launch_bounds__(256) void merge_w_kernel(const float* __restrict__ W,
                                                      const float* __restrict__ down,
                                                      const float* __restrict__ up,
                                                      unsigned short* __restrict__ wb,
                                                      int IN) {
    const int i  = blockIdx.x * 1024 + threadIdx.x * 4;
    const int o0 = blockIdx.y * MW_ROWS;

    float4 u[16];
#pragma unroll
    for (int r = 0; r < 16; r++) u[r] = *(const float4*)(up + r * IN + i);

    for (int o = o0; o < o0 + MW_ROWS; o++) {
        float4 w = *(const float4*)(W + (size_t)o * IN + i);
#pragma unroll
        for (int r = 0; r < 16; r++) {
            const float dr = down[o * 16 + r];   // wave-uniform -> scalar load
            w.x += dr * u[r].x; w.y += dr * u[r].y;
            w.z += dr * u[r].z; w.w += dr * u[r].w;
        }
        union { unsigned short s[4]; uint2 v; } ov;
        ov.s[0] = f2bf_rne(w.x); ov.s[1] = f2bf_rne(w.y);
        ov.s[2] = f2bf_rne(w.z); ov.s[3] = f2bf_rne(w.w);
        *(uint2*)(wb + (size_t)o * IN + i) = ov.v;
    }
}

// ---------------- bf16 gemm_bt, 256x256 tile, BK=64, 8-phase pipelined ----------------
#define BM 256
#define BN 256
#define BK 64

static __device__ __forceinline__ void async16(const void* g, void* l) {
    auto* gp = reinterpret_cast<const __attribute__((address_space(1))) uint32_t*>(
        reinterpret_cast<uintptr_t>(g));
    auto* lp = reinterpret_cast<__attribute__((address_space(3))) uint32_t*>(
        reinterpret_cast<uintptr_t>(l));
    __builtin_amdgcn_global_load_lds(gp, lp, 16 /*bytes*/, 0, 0);
}

// LDS map (128 KiB):
//   A: buf*32768 + half*16384      (2 bufs x 2 halves x 128 rows x 64 bf16)
//   B: 65536 + buf*32768 + half*16384
// Row layout: 64 bf16 = 128 B = 8 granules of 16 B; logical (row, q) stored at
// granule q ^ (row & 7)  => conflict-free ds_read_b128, and the linear DMA dest
// gets the inverse permutation applied to the per-lane *global* source address.
__global__ __launch_bounds__(512, 2) void gemm_bt_bias_kernel(
    const unsigned short* __restrict__ A,   // bf16 [M][K]  (xb)
    const unsigned short* __restrict__ B,   // bf16 [N][K]  (wb)
    const float* __restrict__ bias,         // [N]
    float* __restrict__ C,                  // [M][N]
    int M, int N, int K) {
    __shared__ __align__(16) unsigned char smem[131072];

    const int tid  = threadIdx.x;
    const int wave = tid >> 6;
    const int lane = tid & 63;
    const int wm   = wave >> 2;      // 0..1 : M-half of tile
    const int wn   = wave & 3;       // 0..3 : N-quarter of tile
    const int quad = lane >> 4;      // 0..3
    const int l16  = lane & 15;

    // bijective XCD swizzle (gridDim.x = 512, divisible by 8)
    const int nwg = gridDim.x;
    const int bid = blockIdx.x;
    const int swz = (bid & 7) * (nwg >> 3) + (bid >> 3);
    const int ntn = N / BN;
    const int tileM = (swz / ntn) * BM;
    const int tileN = (swz % ntn) * BN;

    const int nt = K / BK;           // 64, power of two

    // ---- staging: linear LDS dest (wave base + lane*16), pre-swizzled global src ----
    const int trow = tid >> 3;                          // 0..63
    const int tcol = ((tid & 7) ^ (trow & 7)) << 3;     // element offset in row
    const unsigned short* aG = A + (size_t)(tileM + trow) * K + tcol;
    const unsigned short* bG = B + (size_t)(tileN + trow) * K + tcol;
    unsigned char* ldst = smem + tid * 16;

#define STAGE_A(tk, h) do {                                                   \
        const size_t kof = (size_t)(((tk) & (nt - 1)) * BK);                  \
        unsigned char* d = ldst + (((tk) & 1) * 32768 + (h) * 16384);         \
        async16(aG + (size_t)((h) * 128) * K + kof, d);                       \
        async16(aG + (size_t)((h) * 128 + 64) * K + kof, d + 8192);           \
    } while (0)
#define STAGE_B(tk, h) do {                                                   \
        const size_t kof = (size_t)(((tk) & (nt - 1)) * BK);                  \
        unsigned char* d = ldst + (65536 + ((tk) & 1) * 32768 + (h) * 16384); \
        async16(bG + (size_t)((h) * 128) * K + kof, d);                       \
        async16(bG + (size_t)((h) * 128 + 64) * K + kof, d + 8192);           \
    } while (0)

    // ---- fragment read offsets (granule-XOR swizzle, conflict-free) ----
    const int qs0 = ((0 * 4 + quad) ^ (l16 & 7)) * 16;   // k-step 0
    const int qs1 = ((1 * 4 + quad) ^ (l16 & 7)) * 16;   // k-step 1
    const int arowb = l16 * 128;                          // + m*2048
    const int browb = ((wn & 1) * 64 + l16) * 128;        // + n*2048

    floatx4 acc[8][4];
#pragma unroll
    for (int i = 0; i < 8; i++)
#pragma unroll
        for (int j = 0; j < 4; j++) acc[i][j] = (floatx4)(0.0f);

    // ---- prologue: kt0 fully staged (8 loads) + kt1.B (4 loads) ----
    STAGE_A(0, 0); STAGE_A(0, 1); STAGE_B(0, 0); STAGE_B(0, 1);
    STAGE_B(1, 0); STAGE_B(1, 1);
    asm volatile("s_waitcnt vmcnt(4)" ::: "memory");   // kt0 landed, kt1.B in flight
    __builtin_amdgcn_s_barrier();

#define MFMA8(mA, mB)                                                          \
    _Pragma("unroll")                                                          \
    for (int n = 0; n < 4; n++) {                                              \
        acc[mA][n] = __builtin_amdgcn_mfma_f32_16x16x32_bf16(aA0, b0[n], acc[mA][n], 0, 0, 0); \
        acc[mA][n] = __builtin_amdgcn_mfma_f32_16x16x32_bf16(aA1, b1[n], acc[mA][n], 0, 0, 0); \
        acc[mB][n] = __builtin_amdgcn_mfma_f32_16x16x32_bf16(aB0, b0[n], acc[mB][n], 0, 0, 0); \
        acc[mB][n] = __builtin_amdgcn_mfma_f32_16x16x32_bf16(aB1, b1[n], acc[mB][n], 0, 0, 0); \
    }

#pragma unroll 2
    for (int kt = 0; kt < nt; ++kt) {
        const int cur = kt & 1;
        const unsigned char* Ab = smem + (cur * 32768 + wm * 16384 + arowb);
        const unsigned char* Bb = smem + (65536 + cur * 32768 + (wn >> 1) * 16384 + browb);

        bf16x8 b0[4], b1[4];
        bf16x8 aA0, aA1, aB0, aB1;

        // ---------- phase 0 : all B frags -> regs, MFMA m0,m1 ----------
#pragma unroll
        for (int n = 0; n < 4; n++) {
            b0[n] = *(const bf16x8*)(Bb + n * 2048 + qs0);
            b1[n] = *(const bf16x8*)(Bb + n * 2048 + qs1);
        }
        aA0 = *(const bf16x8*)(Ab + 0 * 2048 + qs0);
        aA1 = *(const bf16x8*)(Ab + 0 * 2048 + qs1);
        aB0 = *(const bf16x8*)(Ab + 1 * 2048 + qs0);
        aB1 = *(const bf16x8*)(Ab + 1 * 2048 + qs1);
        STAGE_A(kt + 1, 0);                  // other buffer's A: free since kt-1 end
        __builtin_amdgcn_s_barrier();
        __builtin_amdgcn_s_setprio(1);
        MFMA8(0, 1);
        __builtin_amdgcn_s_setprio(0);
        __builtin_amdgcn_s_barrier();

        // ---------- phase 1 : MFMA m2,m3 ----------
        aA0 = *(const bf16x8*)(Ab + 2 * 2048 + qs0);
        aA1 = *(const bf16x8*)(Ab + 2 * 2048 + qs1);
        aB0 = *(const bf16x8*)(Ab + 3 * 2048 + qs0);
        aB1 = *(const bf16x8*)(Ab + 3 * 2048 + qs1);
        STAGE_A(kt + 1, 1);
        __builtin_amdgcn_s_barrier();
        __builtin_amdgcn_s_setprio(1);
        MFMA8(2, 3);
        __builtin_amdgcn_s_setprio(0);
        __builtin_amdgcn_s_barrier();

        // ---------- phase 2 : MFMA m4,m5 ----------
        aA0 = *(const bf16x8*)(Ab + 4 * 2048 + qs0);
        aA1 = *(const bf16x8*)(Ab + 4 * 2048 + qs1);
        aB0 = *(const bf16x8*)(Ab + 5 * 2048 + qs0);
        aB1 = *(const bf16x8*)(Ab + 5 * 2048 + qs1);
        STAGE_B(kt + 2, 0);                  // current buffer's B: dead after phase 0
        __builtin_amdgcn_s_barrier();
        __builtin_amdgcn_s_setprio(1);
        MFMA8(4, 5);
        __builtin_amdgcn_s_setprio(0);
        __builtin_amdgcn_s_barrier();

        // ---------- phase 3 : MFMA m6,m7, counted vmcnt ----------
        aA0 = *(const bf16x8*)(Ab + 6 * 2048 + qs0);
        aA1 = *(const bf16x8*)(Ab + 6 * 2048 + qs1);
        aB0 = *(const bf16x8*)(Ab + 7 * 2048 + qs0);
        aB1 = *(const bf16x8*)(Ab + 7 * 2048 + qs1);
        STAGE_B(kt + 2, 1);
        __builtin_amdgcn_s_barrier();
        __builtin_amdgcn_s_setprio(1);
        MFMA8(6, 7);
        __builtin_amdgcn_s_setprio(0);
        // all of kt+1 (A issued phases 0-1, B issued at kt-1) landed;
        // kt+2's 4 B loads stay in flight -- never drain to 0.
        asm volatile("s_waitcnt vmcnt(4)" ::: "memory");
        __builtin_amdgcn_s_barrier();
    }

    // drain the overhanging prefetches before LDS can be reassigned
    asm volatile("s_waitcnt vmcnt(0)" ::: "memory");

    // ---- epilogue: C/D layout col=lane&15, row=quad*4+reg ----
    float bv[4];
#pragma unroll
    for (int n = 0; n < 4; n++) bv[n] = bias[tileN + wn * 64 + n * 16 + l16];

#pragma unroll
    for (int m = 0; m < 8; m++) {
#pragma unroll
        for (int r = 0; r < 4; r++) {
            const int row = tileM + wm * 128 + m * 16 + quad * 4 + r;
            float* crow = C + (size_t)row * N + tileN + wn * 64 + l16;
#pragma unroll
            for (int n = 0; n < 4; n++) crow[n * 16] = acc[m][n][r] + bv[n];
        }
    }
}

extern "C" void kernel_launch(void* const* d_in, const int* in_sizes, int n_in,
                              void* d_out, int out_size, void* d_ws, size_t ws_size,
                              hipStream_t stream) {
    const float* x    = (const float*)d_in[0];
    const float* W    = (const float*)d_in[1];
    const float* bias = (const float*)d_in[2];
    const float* down = (const float*)d_in[3];
    const float* up   = (const float*)d_in[4];
    float* out = (float*)d_out;

    const int IN  = 4096;                 // K
    const int OUT = 4096;                 // N
    const int M   = in_sizes[0] / IN;     // 8192

    unsigned short* xb = (unsigned short*)d_ws;                  // M*K bf16
    unsigned short* wb = xb + (size_t)M * IN;                    // N*K bf16

    const int n4 = M * IN / 4;
    cvt_x_kernel<<<n4 / 2 / 256, 256, 0, stream>>>((const float4*)x, (uint2*)xb, n4);
    dim3 mgrid(IN / 1024, OUT / MW_ROWS);   // (4, 256)
    merge_w_kernel<<<mgrid, 256, 0, stream>>>(W, down, up, wb, IN);

    dim3 grid((M / BM) * (OUT / BN));   // 32*16 = 512, divisible by 8
    gemm_bt_bias_kernel<<<grid, 512, 0, stream>>>(xb, wb, bias, out, M, OUT, IN);
}